// Round 1
// baseline (12292.904 us; speedup 1.0000x reference)
//
#include <hip/hip_runtime.h>
#include <hip/hip_bf16.h>

// Problem constants
#define T_ 512
#define B_ 64
#define I_ 256
#define H_ 512
#define O_ 256
#define NGB 32              // gate blocks (each owns 16 h-cols -> 64 gate cols)
#define NLB 8               // linear-projection blocks (each owns 32 out cols)
#define NBLK (NGB + NLB)
#define NTHR 256
#define BH (B_ * H_)        // elements in one h/c state (64*512)

typedef unsigned short u16;
typedef short bf16x8 __attribute__((ext_vector_type(8)));
typedef float f32x4 __attribute__((ext_vector_type(4)));

// ---- workspace layout (bytes), all 256B aligned ----
#define WS_CNT   0
#define WS_XBF   256                      // x as bf16, plain (T,B,I):      16,777,216
#define WS_WHH1  (WS_XBF   + 16777216)    // W_hh1 frag-ordered:             2,097,152
#define WS_WIH1  (WS_WHH1  + 2097152)     // W_ih1 frag-ordered:             1,048,576
#define WS_WIH2  (WS_WIH1  + 1048576)     // W_ih2 frag-ordered:             2,097,152
#define WS_WHH2  (WS_WIH2  + 2097152)     // W_hh2 frag-ordered:             2,097,152
#define WS_WLIN  (WS_WHH2  + 2097152)     // W_lin frag-ordered:               262,144
#define WS_B1    (WS_WLIN  + 262144)      // b_ih1+b_hh1 f32[2048]:              8,192
#define WS_B2    (WS_B1    + 8192)        // b_ih2+b_hh2 f32[2048]:              8,192
#define WS_H1    (WS_B2    + 8192)        // h1 double buffer bf16 2*BH:       131,072
#define WS_H2    (WS_H1    + 131072)      // h2 double buffer bf16 2*BH:       131,072
#define WS_END   (WS_H2    + 131072)      // ~23.6 MB total

__device__ __forceinline__ u16 f2bf(float f) {
  union { float f; unsigned u; } v; v.f = f;
  unsigned r = v.u + 0x7FFFu + ((v.u >> 16) & 1u);   // round-to-nearest-even
  return (u16)(r >> 16);
}
__device__ __forceinline__ float sigm(float x)  { return 1.0f / (1.0f + __expf(-x)); }
// tanh via exp, saturates correctly at +/-inf (no NaN)
__device__ __forceinline__ float tanh_(float x) { return 1.0f - 2.0f / (__expf(2.0f * x) + 1.0f); }

__device__ __forceinline__ bf16x8 ldg8(const u16* p) { return *(const bf16x8*)p; }
#define MFMA16(a, b, c) __builtin_amdgcn_mfma_f32_16x16x32_bf16((a), (b), (c), 0, 0, 0)

__device__ __forceinline__ void cvt8(const float* s, u16* dst) {
  bf16x8 v;
  #pragma unroll
  for (int j = 0; j < 8; j++) v[j] = (short)f2bf(s[j]);
  *(bf16x8*)dst = v;
}

// Global barrier: monotonically increasing counter; safe across XCDs
// (device-scope RMW + release/acquire fences). Requires co-residency
// (cooperative launch).
__device__ __forceinline__ void gbar(unsigned* cnt, unsigned target) {
  __syncthreads();
  if (threadIdx.x == 0) {
    __threadfence();   // release: make h-stores visible device-wide
    __hip_atomic_fetch_add(cnt, 1u, __ATOMIC_RELAXED, __HIP_MEMORY_SCOPE_AGENT);
    while (__hip_atomic_load(cnt, __ATOMIC_RELAXED, __HIP_MEMORY_SCOPE_AGENT) < target)
      __builtin_amdgcn_s_sleep(2);
    __threadfence();   // acquire: invalidate stale cached h
  }
  __syncthreads();
}

// K=512 recurrent GEMM slice: 16 k-tiles, 4 gate n-tiles from frag-ordered W.
__device__ __forceinline__ void gemm4(const u16* __restrict__ hr, const u16* __restrict__ wsrc,
                                      int lane, f32x4& aI, f32x4& aF, f32x4& aG, f32x4& aO) {
  #pragma unroll 8
  for (int kt = 0; kt < 16; kt++) {
    bf16x8 a = ldg8(hr + kt * 32);
    aI = MFMA16(a, ldg8(wsrc + (0 * 16 + kt) * 512 + lane * 8), aI);
    aF = MFMA16(a, ldg8(wsrc + (1 * 16 + kt) * 512 + lane * 8), aF);
    aG = MFMA16(a, ldg8(wsrc + (2 * 16 + kt) * 512 + lane * 8), aG);
    aO = MFMA16(a, ldg8(wsrc + (3 * 16 + kt) * 512 + lane * 8), aO);
  }
}

// K=256 input-projection partial (x static -> runs pre-barrier, off critical path)
__device__ __forceinline__ void xpart8(const u16* __restrict__ xb, const u16* __restrict__ wsrc,
                                       int lane, f32x4& pI, f32x4& pF, f32x4& pG, f32x4& pO) {
  #pragma unroll
  for (int kt = 0; kt < 8; kt++) {
    bf16x8 a = ldg8(xb + kt * 32);
    pI = MFMA16(a, ldg8(wsrc + (0 * 8 + kt) * 512 + lane * 8), pI);
    pF = MFMA16(a, ldg8(wsrc + (1 * 8 + kt) * 512 + lane * 8), pF);
    pG = MFMA16(a, ldg8(wsrc + (2 * 8 + kt) * 512 + lane * 8), pG);
    pO = MFMA16(a, ldg8(wsrc + (3 * 8 + kt) * 512 + lane * 8), pO);
  }
}

// gate order i,f,g,o (PyTorch). c in registers; h written bf16.
__device__ __forceinline__ void cellup(const f32x4& aI, const f32x4& aF, const f32x4& aG,
                                       const f32x4& aO, f32x4& cS, u16* hw) {
  #pragma unroll
  for (int r = 0; r < 4; r++) {
    float cn = sigm(aF[r]) * cS[r] + sigm(aI[r]) * tanh_(aG[r]);
    cS[r] = cn;
    hw[r * 512] = f2bf(sigm(aO[r]) * tanh_(cn));
  }
}

__global__ void init_cnt(unsigned* cnt) { if (threadIdx.x == 0) *cnt = 0u; }

__global__ void __launch_bounds__(NTHR, 1) lstm_ae_kernel(
    const float* __restrict__ xin,
    const float* __restrict__ Wih1, const float* __restrict__ Whh1,
    const float* __restrict__ bih1, const float* __restrict__ bhh1,
    const float* __restrict__ Wih2, const float* __restrict__ Whh2,
    const float* __restrict__ bih2, const float* __restrict__ bhh2,
    const float* __restrict__ Wlin, const float* __restrict__ blin,
    const float* __restrict__ h10, const float* __restrict__ c10,
    const float* __restrict__ h20, const float* __restrict__ c20,
    float* __restrict__ out, char* __restrict__ ws) {
  unsigned* cnt = (unsigned*)(ws + WS_CNT);
  u16* xbf   = (u16*)(ws + WS_XBF);
  u16* whh1f = (u16*)(ws + WS_WHH1);
  u16* wih1f = (u16*)(ws + WS_WIH1);
  u16* wih2f = (u16*)(ws + WS_WIH2);
  u16* whh2f = (u16*)(ws + WS_WHH2);
  u16* wlinf = (u16*)(ws + WS_WLIN);
  float* b1  = (float*)(ws + WS_B1);
  float* b2  = (float*)(ws + WS_B2);
  u16* h1b   = (u16*)(ws + WS_H1);
  u16* h2b   = (u16*)(ws + WS_H2);

  const int tid = blockIdx.x * NTHR + threadIdx.x;

  // ---------------- phase 0: convert/pack everything ----------------
  // x -> bf16 (plain layout)
  for (int c = tid; c < T_ * B_ * I_ / 8; c += NBLK * NTHR)
    cvt8(xin + c * 8, xbf + c * 8);
  // W_hh1 frag-ordered: [n:32][g:4][kt:16][lane:64][8]
  for (int c = tid; c < (1 << 17); c += NBLK * NTHR) {
    int lane = c & 63, kt = (c >> 6) & 15, g = (c >> 10) & 3, n = c >> 12;
    int row = g * 512 + n * 16 + (lane & 15);
    int k   = kt * 32 + (lane >> 4) * 8;
    cvt8(Whh1 + row * 512 + k, whh1f + c * 8);
  }
  // W_ih1 frag-ordered: [n:32][g:4][kt:8][lane:64][8]
  for (int c = tid; c < (1 << 16); c += NBLK * NTHR) {
    int lane = c & 63, kt = (c >> 6) & 7, g = (c >> 9) & 3, n = c >> 11;
    int row = g * 512 + n * 16 + (lane & 15);
    int k   = kt * 32 + (lane >> 4) * 8;
    cvt8(Wih1 + row * 256 + k, wih1f + c * 8);
  }
  // W_ih2 / W_hh2 frag-ordered (same shape as W_hh1)
  for (int c = tid; c < (1 << 17); c += NBLK * NTHR) {
    int lane = c & 63, kt = (c >> 6) & 15, g = (c >> 10) & 3, n = c >> 12;
    int row = g * 512 + n * 16 + (lane & 15);
    int k   = kt * 32 + (lane >> 4) * 8;
    cvt8(Wih2 + row * 512 + k, wih2f + c * 8);
    cvt8(Whh2 + row * 512 + k, whh2f + c * 8);
  }
  // W_lin frag-ordered: [l:8][nt:2][kt:16][lane:64][8]
  for (int c = tid; c < (1 << 14); c += NBLK * NTHR) {
    int lane = c & 63, kt = (c >> 6) & 15, nt = (c >> 10) & 1, l = c >> 11;
    int row = l * 32 + nt * 16 + (lane & 15);
    int k   = kt * 32 + (lane >> 4) * 8;
    cvt8(Wlin + row * 512 + k, wlinf + c * 8);
  }
  // initial hidden states -> bf16 buffer 0
  for (int c = tid; c < BH / 8; c += NBLK * NTHR) {
    cvt8(h10 + c * 8, h1b + c * 8);
    cvt8(h20 + c * 8, h2b + c * 8);
  }
  // fused biases
  for (int i2 = tid; i2 < 2048; i2 += NBLK * NTHR) {
    b1[i2] = bih1[i2] + bhh1[i2];
    b2[i2] = bih2[i2] + bhh2[i2];
  }

  unsigned bar = 0;
  gbar(cnt, (++bar) * NBLK);   // B0: packed data visible everywhere

  const int lane = threadIdx.x & 63;
  const int wv   = threadIdx.x >> 6;     // wave = m-tile (16 batch rows)
  const int l15  = lane & 15;
  const int qd   = lane >> 4;
  const int row0 = wv * 16 + qd * 4;     // C-frag row base (batch)
  const int aoff512 = (wv * 16 + l15) * 512 + qd * 8;  // A-frag offset in (64,512) bf16
  const int aoff256 = (wv * 16 + l15) * 256 + qd * 8;  // A-frag offset in (64,256) bf16

  if (blockIdx.x < NGB) {
    // ======================= gate blocks =======================
    const int n = blockIdx.x;
    const u16* whh1s = whh1f + n * 32768;
    const u16* wih1s = wih1f + n * 16384;
    const u16* wih2s = wih2f + n * 32768;
    const u16* whh2s = whh2f + n * 32768;
    const int hcol = n * 16 + l15;
    const float bI = b1[0 * 512 + hcol], bF = b1[1 * 512 + hcol];
    const float bG = b1[2 * 512 + hcol], bO = b1[3 * 512 + hcol];
    f32x4 cS;
    #pragma unroll
    for (int r = 0; r < 4; r++) cS[r] = c10[(row0 + r) * 512 + hcol];

    // x-partial for t=0
    f32x4 pI = {bI, bI, bI, bI}, pF = {bF, bF, bF, bF};
    f32x4 pG = {bG, bG, bG, bG}, pO = {bO, bO, bO, bO};
    xpart8(xbf + aoff256, wih1s, lane, pI, pF, pG, pO);

    // -------- phase 1: encoder LSTM --------
    for (int t = 0; t < T_; t++) {
      f32x4 aI = pI, aF = pF, aG = pG, aO = pO;
      gemm4(h1b + (t & 1) * BH + aoff512, whh1s, lane, aI, aF, aG, aO);
      cellup(aI, aF, aG, aO, cS, h1b + ((t + 1) & 1) * BH + row0 * 512 + hcol);
      if (t + 1 < T_) {   // prefetch-compute next x-projection before barrier
        pI = {bI, bI, bI, bI}; pF = {bF, bF, bF, bF};
        pG = {bG, bG, bG, bG}; pO = {bO, bO, bO, bO};
        xpart8(xbf + (t + 1) * 16384 + aoff256, wih1s, lane, pI, pF, pG, pO);
      }
      gbar(cnt, (++bar) * NBLK);
    }

    // -------- phase 2: xp2 = h1T @ W_ih2^T + b2 (constant over decoder) --------
    const float bI2 = b2[0 * 512 + hcol], bF2 = b2[1 * 512 + hcol];
    const float bG2 = b2[2 * 512 + hcol], bO2 = b2[3 * 512 + hcol];
    f32x4 qI = {bI2, bI2, bI2, bI2}, qF = {bF2, bF2, bF2, bF2};
    f32x4 qG = {bG2, bG2, bG2, bG2}, qO = {bO2, bO2, bO2, bO2};
    gemm4(h1b + 0 + aoff512, wih2s, lane, qI, qF, qG, qO);   // h1T is in buf 0
    #pragma unroll
    for (int r = 0; r < 4; r++) cS[r] = c20[(row0 + r) * 512 + hcol];
    gbar(cnt, (++bar) * NBLK);   // B_mid

    // -------- phase 3: decoder LSTM --------
    for (int t = 0; t < T_; t++) {
      f32x4 aI = qI, aF = qF, aG = qG, aO = qO;
      gemm4(h2b + (t & 1) * BH + aoff512, whh2s, lane, aI, aF, aG, aO);
      cellup(aI, aF, aG, aO, cS, h2b + ((t + 1) & 1) * BH + row0 * 512 + hcol);
      gbar(cnt, (++bar) * NBLK);
    }
  } else {
    // ======================= linear blocks =======================
    const int l = blockIdx.x - NGB;
    const u16* wlins = wlinf + l * 16384;
    const float bl0 = blin[l * 32 + l15], bl1 = blin[l * 32 + 16 + l15];

    for (int i3 = 0; i3 < T_ + 1; i3++) gbar(cnt, (++bar) * NBLK);  // phase1 + B_mid

    // lag-1 pipeline: during decoder interval t compute out[t-1]
    for (int t = 0; t < T_; t++) {
      if (t >= 1) {
        const u16* hr = h2b + (t & 1) * BH + aoff512;
        f32x4 q0 = {bl0, bl0, bl0, bl0}, q1 = {bl1, bl1, bl1, bl1};
        #pragma unroll 8
        for (int kt = 0; kt < 16; kt++) {
          bf16x8 a = ldg8(hr + kt * 32);
          q0 = MFMA16(a, ldg8(wlins + (0 * 16 + kt) * 512 + lane * 8), q0);
          q1 = MFMA16(a, ldg8(wlins + (1 * 16 + kt) * 512 + lane * 8), q1);
        }
        float* op = out + ((t - 1) * 64 + row0) * 256 + l * 32 + l15;
        #pragma unroll
        for (int r = 0; r < 4; r++) { op[r * 256] = q0[r]; op[r * 256 + 16] = q1[r]; }
      }
      gbar(cnt, (++bar) * NBLK);
    }
    {   // trailing: out[T-1] from h2 final state (buf 0)
      const u16* hr = h2b + 0 + aoff512;
      f32x4 q0 = {bl0, bl0, bl0, bl0}, q1 = {bl1, bl1, bl1, bl1};
      #pragma unroll 8
      for (int kt = 0; kt < 16; kt++) {
        bf16x8 a = ldg8(hr + kt * 32);
        q0 = MFMA16(a, ldg8(wlins + (0 * 16 + kt) * 512 + lane * 8), q0);
        q1 = MFMA16(a, ldg8(wlins + (1 * 16 + kt) * 512 + lane * 8), q1);
      }
      float* op = out + ((T_ - 1) * 64 + row0) * 256 + l * 32 + l15;
      #pragma unroll
      for (int r = 0; r < 4; r++) { op[r * 256] = q0[r]; op[r * 256 + 16] = q1[r]; }
    }
  }
}

extern "C" void kernel_launch(void* const* d_in, const int* in_sizes, int n_in,
                              void* d_out, int out_size, void* d_ws, size_t ws_size,
                              hipStream_t stream) {
  (void)in_sizes; (void)n_in; (void)out_size; (void)ws_size;
  const float* xin  = (const float*)d_in[0];
  const float* Wih1 = (const float*)d_in[1];
  const float* Whh1 = (const float*)d_in[2];
  const float* bih1 = (const float*)d_in[3];
  const float* bhh1 = (const float*)d_in[4];
  const float* Wih2 = (const float*)d_in[5];
  const float* Whh2 = (const float*)d_in[6];
  const float* bih2 = (const float*)d_in[7];
  const float* bhh2 = (const float*)d_in[8];
  const float* Wlin = (const float*)d_in[9];
  const float* blin = (const float*)d_in[10];
  const float* h10  = (const float*)d_in[11];
  const float* c10  = (const float*)d_in[12];
  const float* h20  = (const float*)d_in[13];
  const float* c20  = (const float*)d_in[14];
  float* out = (float*)d_out;
  char* ws   = (char*)d_ws;
  unsigned* cnt = (unsigned*)ws;

  init_cnt<<<dim3(1), dim3(64), 0, stream>>>(cnt);

  void* args[] = { (void*)&xin, (void*)&Wih1, (void*)&Whh1, (void*)&bih1, (void*)&bhh1,
                   (void*)&Wih2, (void*)&Whh2, (void*)&bih2, (void*)&bhh2,
                   (void*)&Wlin, (void*)&blin, (void*)&h10, (void*)&c10,
                   (void*)&h20, (void*)&c20, (void*)&out, (void*)&ws };
  hipLaunchCooperativeKernel((void*)lstm_ae_kernel, dim3(NBLK), dim3(NTHR),
                             args, 0, stream);
}

// Round 2
// 10568.790 us; speedup vs baseline: 1.1631x; 1.1631x over previous
//
#include <hip/hip_runtime.h>
#include <hip/hip_bf16.h>

// Problem constants
#define T_ 512
#define B_ 64
#define I_ 256
#define H_ 512
#define O_ 256
#define NGB 128             // gate blocks: 32 hcol-tiles x 4 m-tiles; 4 waves = 4 gates
#define NLB 16              // linear blocks: 16 n-tiles; 4 waves = 4 m-tiles
#define NBLK (NGB + NLB)
#define NTHR 256
#define BH (B_ * H_)

typedef unsigned short u16;
typedef short bf16x8 __attribute__((ext_vector_type(8)));   // 16 B = 4 VGPRs
typedef float f32x4 __attribute__((ext_vector_type(4)));

// ---- workspace layout (bytes) ----
#define WS_CNT   0
#define WS_XBF   256
#define WS_WHH1  (WS_XBF   + 16777216)
#define WS_WIH1  (WS_WHH1  + 2097152)
#define WS_WIH2  (WS_WIH1  + 1048576)
#define WS_WHH2  (WS_WIH2  + 2097152)
#define WS_WLIN  (WS_WHH2  + 2097152)
#define WS_B1    (WS_WLIN  + 262144)
#define WS_B2    (WS_B1    + 8192)
#define WS_H1    (WS_B2    + 8192)
#define WS_H2    (WS_H1    + 131072)
#define WS_END   (WS_H2    + 131072)

__device__ __forceinline__ u16 f2bf(float f) {
  union { float f; unsigned u; } v; v.f = f;
  unsigned r = v.u + 0x7FFFu + ((v.u >> 16) & 1u);
  return (u16)(r >> 16);
}
__device__ __forceinline__ float sigm(float x)  { return 1.0f / (1.0f + __expf(-x)); }
__device__ __forceinline__ float tanh_(float x) { return 1.0f - 2.0f / (__expf(2.0f * x) + 1.0f); }
__device__ __forceinline__ bf16x8 ldg8(const u16* p) { return *(const bf16x8*)p; }
#define MFMA16(a, b, c) __builtin_amdgcn_mfma_f32_16x16x32_bf16((a), (b), (c), 0, 0, 0)

__device__ __forceinline__ void cvt8(const float* s, u16* dst) {
  bf16x8 v;
  #pragma unroll
  for (int j = 0; j < 8; j++) v[j] = (short)f2bf(s[j]);
  *(bf16x8*)dst = v;
}

// Global barrier: monotonic counter, device-scope (worked in R1; keep).
__device__ __forceinline__ void gbar(unsigned* cnt, unsigned target) {
  __syncthreads();
  if (threadIdx.x == 0) {
    __threadfence();
    __hip_atomic_fetch_add(cnt, 1u, __ATOMIC_RELAXED, __HIP_MEMORY_SCOPE_AGENT);
    while (__hip_atomic_load(cnt, __ATOMIC_RELAXED, __HIP_MEMORY_SCOPE_AGENT) < target)
      __builtin_amdgcn_s_sleep(2);
    __threadfence();
  }
  __syncthreads();
}

__global__ void init_cnt(unsigned* cnt) { if (threadIdx.x == 0) *cnt = 0u; }

__global__ void __launch_bounds__(NTHR, 1) lstm_ae_kernel(
    const float* __restrict__ xin,
    const float* __restrict__ Wih1, const float* __restrict__ Whh1,
    const float* __restrict__ bih1, const float* __restrict__ bhh1,
    const float* __restrict__ Wih2, const float* __restrict__ Whh2,
    const float* __restrict__ bih2, const float* __restrict__ bhh2,
    const float* __restrict__ Wlin, const float* __restrict__ blin,
    const float* __restrict__ h10, const float* __restrict__ c10,
    const float* __restrict__ h20, const float* __restrict__ c20,
    float* __restrict__ out, char* __restrict__ ws) {
  unsigned* cnt = (unsigned*)(ws + WS_CNT);
  u16* xbf   = (u16*)(ws + WS_XBF);
  u16* whh1f = (u16*)(ws + WS_WHH1);
  u16* wih1f = (u16*)(ws + WS_WIH1);
  u16* wih2f = (u16*)(ws + WS_WIH2);
  u16* whh2f = (u16*)(ws + WS_WHH2);
  u16* wlinf = (u16*)(ws + WS_WLIN);
  float* b1  = (float*)(ws + WS_B1);
  float* b2  = (float*)(ws + WS_B2);
  u16* h1b   = (u16*)(ws + WS_H1);
  u16* h2b   = (u16*)(ws + WS_H2);

  __shared__ float plds[1024];   // 4 gates x 16x16 preacts

  const int tid = blockIdx.x * NTHR + threadIdx.x;

  // ---------------- phase 0: convert/pack (same packing as R1, proven) ----------
  for (int c = tid; c < T_ * B_ * I_ / 8; c += NBLK * NTHR)
    cvt8(xin + c * 8, xbf + c * 8);
  for (int c = tid; c < (1 << 17); c += NBLK * NTHR) {
    int lane = c & 63, kt = (c >> 6) & 15, g = (c >> 10) & 3, n = c >> 12;
    int row = g * 512 + n * 16 + (lane & 15);
    int k   = kt * 32 + (lane >> 4) * 8;
    cvt8(Whh1 + row * 512 + k, whh1f + c * 8);
  }
  for (int c = tid; c < (1 << 16); c += NBLK * NTHR) {
    int lane = c & 63, kt = (c >> 6) & 7, g = (c >> 9) & 3, n = c >> 11;
    int row = g * 512 + n * 16 + (lane & 15);
    int k   = kt * 32 + (lane >> 4) * 8;
    cvt8(Wih1 + row * 256 + k, wih1f + c * 8);
  }
  for (int c = tid; c < (1 << 17); c += NBLK * NTHR) {
    int lane = c & 63, kt = (c >> 6) & 15, g = (c >> 10) & 3, n = c >> 12;
    int row = g * 512 + n * 16 + (lane & 15);
    int k   = kt * 32 + (lane >> 4) * 8;
    cvt8(Wih2 + row * 512 + k, wih2f + c * 8);
    cvt8(Whh2 + row * 512 + k, whh2f + c * 8);
  }
  for (int c = tid; c < (1 << 14); c += NBLK * NTHR) {
    int lane = c & 63, kt = (c >> 6) & 15, nt = (c >> 10) & 1, l = c >> 11;
    int row = l * 32 + nt * 16 + (lane & 15);
    int k   = kt * 32 + (lane >> 4) * 8;
    cvt8(Wlin + row * 512 + k, wlinf + c * 8);
  }
  for (int c = tid; c < BH / 8; c += NBLK * NTHR) {
    cvt8(h10 + c * 8, h1b + c * 8);
    cvt8(h20 + c * 8, h2b + c * 8);
  }
  for (int i2 = tid; i2 < 2048; i2 += NBLK * NTHR) {
    b1[i2] = bih1[i2] + bhh1[i2];
    b2[i2] = bih2[i2] + bhh2[i2];
  }

  unsigned bar = 0;
  gbar(cnt, (++bar) * NBLK);   // B0: packed data visible everywhere

  const int lane = threadIdx.x & 63;
  const int wv   = threadIdx.x >> 6;
  const int l15  = lane & 15;
  const int qd   = lane >> 4;

  if (blockIdx.x < NGB) {
    // ================= gate blocks: (nt, mt) tile, wave = gate =================
    const int nt = blockIdx.x >> 2;          // 0..31 hcol-tile
    const int mt = blockIdx.x & 3;           // 0..3  batch-tile
    const int g  = wv;                       // gate i/f/g/o
    const int hcol   = nt * 16 + l15;
    const int ah_off = (mt * 16 + l15) * 512 + qd * 8;   // A-frag offset in (64,512)
    const int ax_off = (mt * 16 + l15) * 256 + qd * 8;   // A-frag offset in (64,256)
    const int row  = threadIdx.x >> 4;       // cell-update ownership: 16x16 tile
    const int col  = threadIdx.x & 15;
    const int crow = mt * 16 + row;
    const int ccol = nt * 16 + col;

    // register-resident weights for the whole encoder
    bf16x8 Wr[16], Wx[8];
    #pragma unroll
    for (int kt = 0; kt < 16; kt++)
      Wr[kt] = ldg8(whh1f + ((nt * 4 + g) * 16 + kt) * 512 + lane * 8);
    #pragma unroll
    for (int kt = 0; kt < 8; kt++)
      Wx[kt] = ldg8(wih1f + ((nt * 4 + g) * 8 + kt) * 512 + lane * 8);

    const float bg = b1[g * 512 + hcol];
    float cS = c10[crow * 512 + ccol];

    // x-partial for t=0
    f32x4 p = {bg, bg, bg, bg};
    #pragma unroll
    for (int kt = 0; kt < 8; kt++)
      p = MFMA16(ldg8(xbf + ax_off + kt * 32), Wx[kt], p);

    // -------- encoder --------
    for (int t = 0; t < T_; t++) {
      const u16* hr = h1b + (t & 1) * BH + ah_off;
      bf16x8 ah[16];
      #pragma unroll
      for (int kt = 0; kt < 16; kt++) ah[kt] = ldg8(hr + kt * 32);
      const int t2 = (t + 1 < T_) ? t + 1 : 0;
      const u16* xr = xbf + t2 * (B_ * I_) + ax_off;
      bf16x8 ax[8];
      #pragma unroll
      for (int kt = 0; kt < 8; kt++) ax[kt] = ldg8(xr + kt * 32);

      f32x4 acc = p;
      #pragma unroll
      for (int kt = 0; kt < 16; kt++) acc = MFMA16(ah[kt], Wr[kt], acc);

      #pragma unroll
      for (int r = 0; r < 4; r++) plds[g * 256 + (qd * 4 + r) * 16 + l15] = acc[r];
      __syncthreads();
      {
        float gi = plds[threadIdx.x], gf = plds[256 + threadIdx.x];
        float gg = plds[512 + threadIdx.x], go = plds[768 + threadIdx.x];
        cS = sigm(gf) * cS + sigm(gi) * tanh_(gg);
        h1b[((t + 1) & 1) * BH + crow * 512 + ccol] = f2bf(sigm(go) * tanh_(cS));
      }
      // x-projection for t+1 (frags already in flight/registers)
      p = {bg, bg, bg, bg};
      #pragma unroll
      for (int kt = 0; kt < 8; kt++) p = MFMA16(ax[kt], Wx[kt], p);

      gbar(cnt, (++bar) * NBLK);
    }

    // -------- phase 2: constant decoder input projection; reload W --------
    f32x4 q;
    {
      const float bg2 = b2[g * 512 + hcol];
      q = f32x4{bg2, bg2, bg2, bg2};
      const u16* hr = h1b + 0 + ah_off;   // h1T lives in buffer 0 (T even)
      #pragma unroll
      for (int kt = 0; kt < 16; kt++)
        q = MFMA16(ldg8(hr + kt * 32),
                   ldg8(wih2f + ((nt * 4 + g) * 16 + kt) * 512 + lane * 8), q);
      #pragma unroll
      for (int kt = 0; kt < 16; kt++)
        Wr[kt] = ldg8(whh2f + ((nt * 4 + g) * 16 + kt) * 512 + lane * 8);
      cS = c20[crow * 512 + ccol];
    }
    gbar(cnt, (++bar) * NBLK);   // B_mid

    // -------- decoder --------
    for (int t = 0; t < T_; t++) {
      const u16* hr = h2b + (t & 1) * BH + ah_off;
      bf16x8 ah[16];
      #pragma unroll
      for (int kt = 0; kt < 16; kt++) ah[kt] = ldg8(hr + kt * 32);
      f32x4 acc = q;
      #pragma unroll
      for (int kt = 0; kt < 16; kt++) acc = MFMA16(ah[kt], Wr[kt], acc);
      #pragma unroll
      for (int r = 0; r < 4; r++) plds[g * 256 + (qd * 4 + r) * 16 + l15] = acc[r];
      __syncthreads();
      {
        float gi = plds[threadIdx.x], gf = plds[256 + threadIdx.x];
        float gg = plds[512 + threadIdx.x], go = plds[768 + threadIdx.x];
        cS = sigm(gf) * cS + sigm(gi) * tanh_(gg);
        h2b[((t + 1) & 1) * BH + crow * 512 + ccol] = f2bf(sigm(go) * tanh_(cS));
      }
      gbar(cnt, (++bar) * NBLK);
    }
  } else {
    // ================= linear blocks: wave = (n-tile j, m-tile wv) ==============
    const int j = blockIdx.x - NGB;          // 0..15 out n-tile
    const int ah_off = (wv * 16 + l15) * 512 + qd * 8;
    const int row0 = wv * 16 + qd * 4;

    bf16x8 Wl[16];
    #pragma unroll
    for (int kt = 0; kt < 16; kt++)
      Wl[kt] = ldg8(wlinf + (j * 16 + kt) * 512 + lane * 8);
    const float bl = blin[j * 16 + l15];

    for (int i3 = 0; i3 < T_ + 1; i3++) gbar(cnt, (++bar) * NBLK);  // encoder + mid

    // lag-1 pipeline: during decoder interval t compute out[t-1]
    for (int t = 0; t < T_; t++) {
      if (t >= 1) {
        const u16* hr = h2b + (t & 1) * BH + ah_off;
        f32x4 q0 = {bl, bl, bl, bl};
        #pragma unroll
        for (int kt = 0; kt < 16; kt++) q0 = MFMA16(ldg8(hr + kt * 32), Wl[kt], q0);
        float* op = out + ((t - 1) * 64 + row0) * 256 + j * 16 + l15;
        #pragma unroll
        for (int r = 0; r < 4; r++) op[r * 256] = q0[r];
      }
      gbar(cnt, (++bar) * NBLK);
    }
    {   // trailing: out[T-1] from final h2 (buffer 0)
      const u16* hr = h2b + 0 + ah_off;
      f32x4 q0 = {bl, bl, bl, bl};
      #pragma unroll
      for (int kt = 0; kt < 16; kt++) q0 = MFMA16(ldg8(hr + kt * 32), Wl[kt], q0);
      float* op = out + ((T_ - 1) * 64 + row0) * 256 + j * 16 + l15;
      #pragma unroll
      for (int r = 0; r < 4; r++) op[r * 256] = q0[r];
    }
  }
}

extern "C" void kernel_launch(void* const* d_in, const int* in_sizes, int n_in,
                              void* d_out, int out_size, void* d_ws, size_t ws_size,
                              hipStream_t stream) {
  (void)in_sizes; (void)n_in; (void)out_size; (void)ws_size;
  const float* xin  = (const float*)d_in[0];
  const float* Wih1 = (const float*)d_in[1];
  const float* Whh1 = (const float*)d_in[2];
  const float* bih1 = (const float*)d_in[3];
  const float* bhh1 = (const float*)d_in[4];
  const float* Wih2 = (const float*)d_in[5];
  const float* Whh2 = (const float*)d_in[6];
  const float* bih2 = (const float*)d_in[7];
  const float* bhh2 = (const float*)d_in[8];
  const float* Wlin = (const float*)d_in[9];
  const float* blin = (const float*)d_in[10];
  const float* h10  = (const float*)d_in[11];
  const float* c10  = (const float*)d_in[12];
  const float* h20  = (const float*)d_in[13];
  const float* c20  = (const float*)d_in[14];
  float* out = (float*)d_out;
  char* ws   = (char*)d_ws;
  unsigned* cnt = (unsigned*)ws;

  init_cnt<<<dim3(1), dim3(64), 0, stream>>>(cnt);

  void* args[] = { (void*)&xin, (void*)&Wih1, (void*)&Whh1, (void*)&bih1, (void*)&bhh1,
                   (void*)&Wih2, (void*)&Whh2, (void*)&bih2, (void*)&bhh2,
                   (void*)&Wlin, (void*)&blin, (void*)&h10, (void*)&c10,
                   (void*)&h20, (void*)&c20, (void*)&out, (void*)&ws };
  hipLaunchCooperativeKernel((void*)lstm_ae_kernel, dim3(NBLK), dim3(NTHR),
                             args, 0, stream);
}

// Round 4
// 7686.012 us; speedup vs baseline: 1.5994x; 1.3751x over previous
//
#include <hip/hip_runtime.h>
#include <hip/hip_bf16.h>

// Problem constants
#define T_ 512
#define B_ 64
#define I_ 256
#define H_ 512
#define O_ 256
#define NGB 128             // gate blocks: 32 hcol-tiles x 4 m-tiles; 4 waves = 4 gates
#define NLB 16              // linear blocks: 16 n-tiles; 4 waves = 4 m-tiles
#define NBLK (NGB + NLB)
#define NTHR 256
#define BH (B_ * H_)

typedef unsigned short u16;
typedef unsigned int u32;
typedef unsigned long long u64;
typedef short bf16x8 __attribute__((ext_vector_type(8)));   // 16 B = 4 VGPRs
typedef float f32x4 __attribute__((ext_vector_type(4)));

// ---- control block (bytes 0..4095 of ws) ----
#define CT_CNT   1024      // flat step-barrier counter (own cache line)
#define CT_B0    2560      // one-time init barrier counter

// ---- workspace layout (bytes) ----
#define WS_XBF   4096
#define WS_WHH1  (WS_XBF   + 16777216)
#define WS_WIH1  (WS_WHH1  + 2097152)
#define WS_WIH2  (WS_WIH1  + 1048576)
#define WS_WHH2  (WS_WIH2  + 2097152)
#define WS_WLIN  (WS_WHH2  + 2097152)
#define WS_B1    (WS_WLIN  + 262144)
#define WS_B2    (WS_B1    + 8192)
#define WS_H1    (WS_B2    + 8192)
#define WS_H2    (WS_H1    + 131072)
#define WS_END   (WS_H2    + 131072)

__device__ __forceinline__ u16 f2bf(float f) {
  union { float f; unsigned u; } v; v.f = f;
  unsigned r = v.u + 0x7FFFu + ((v.u >> 16) & 1u);
  return (u16)(r >> 16);
}
__device__ __forceinline__ float sigm(float x)  { return 1.0f / (1.0f + __expf(-x)); }
__device__ __forceinline__ float tanh_(float x) { return 1.0f - 2.0f / (__expf(2.0f * x) + 1.0f); }
__device__ __forceinline__ bf16x8 ldg8(const u16* p) { return *(const bf16x8*)p; }
// agent-scope (LLC-coherent) 16B load: bypasses possibly-stale local L2
__device__ __forceinline__ bf16x8 ald8(const u16* p) {
  union { bf16x8 v; u64 q[2]; } u;
  u.q[0] = __hip_atomic_load((u64*)p,     __ATOMIC_RELAXED, __HIP_MEMORY_SCOPE_AGENT);
  u.q[1] = __hip_atomic_load((u64*)p + 1, __ATOMIC_RELAXED, __HIP_MEMORY_SCOPE_AGENT);
  return u.v;
}
#define MFMA16(a, b, c) __builtin_amdgcn_mfma_f32_16x16x32_bf16((a), (b), (c), 0, 0, 0)

__device__ __forceinline__ void cvt8(const float* s, u16* dst) {
  bf16x8 v;
  #pragma unroll
  for (int j = 0; j < 8; j++) v[j] = (short)f2bf(s[j]);
  *(bf16x8*)dst = v;
}

// One-time init barrier (heavy fences OK once: flushes packed weights/x to LLC).
__device__ __forceinline__ void gbar0(u32* cnt, unsigned target) {
  __syncthreads();
  if (threadIdx.x == 0) {
    __threadfence();
    __hip_atomic_fetch_add(cnt, 1u, __ATOMIC_RELAXED, __HIP_MEMORY_SCOPE_AGENT);
    while (__hip_atomic_load(cnt, __ATOMIC_RELAXED, __HIP_MEMORY_SCOPE_AGENT) < target)
      __builtin_amdgcn_s_sleep(2);
    __threadfence();
  }
  __syncthreads();
}

// Per-step flat barrier, fence-free. h moves via agent(sc1/LLC) atomics, so no
// cache maintenance is needed; vmcnt(0) (explicit + the one inside
// __syncthreads) ensures this wave's h-stores completed at LLC before arrival.
// Poll with atomic LOADs (not RMWs) to avoid serializing the LLC line.
__device__ __forceinline__ void gbarF(u32* cnt, unsigned target) {
  asm volatile("s_waitcnt vmcnt(0)" ::: "memory");
  __syncthreads();
  if (threadIdx.x == 0) {
    unsigned old = __hip_atomic_fetch_add(cnt, 1u, __ATOMIC_RELAXED,
                                          __HIP_MEMORY_SCOPE_AGENT);
    if (old != target - 1) {
      while (__hip_atomic_load(cnt, __ATOMIC_RELAXED, __HIP_MEMORY_SCOPE_AGENT) < target)
        __builtin_amdgcn_s_sleep(4);
    }
  }
  __syncthreads();
}

__global__ void init_cnt(char* ws) {
  for (int i = threadIdx.x; i < 1024; i += 256)
    __hip_atomic_store((u32*)ws + i, 0u, __ATOMIC_RELAXED, __HIP_MEMORY_SCOPE_AGENT);
}

__global__ void __launch_bounds__(NTHR, 1) lstm_ae_kernel(
    const float* __restrict__ xin,
    const float* __restrict__ Wih1, const float* __restrict__ Whh1,
    const float* __restrict__ bih1, const float* __restrict__ bhh1,
    const float* __restrict__ Wih2, const float* __restrict__ Whh2,
    const float* __restrict__ bih2, const float* __restrict__ bhh2,
    const float* __restrict__ Wlin, const float* __restrict__ blin,
    const float* __restrict__ h10, const float* __restrict__ c10,
    const float* __restrict__ h20, const float* __restrict__ c20,
    float* __restrict__ out, char* __restrict__ ws) {
  char* ctrl = ws;
  u32* cnt   = (u32*)(ctrl + CT_CNT);
  u16* xbf   = (u16*)(ws + WS_XBF);
  u16* whh1f = (u16*)(ws + WS_WHH1);
  u16* wih1f = (u16*)(ws + WS_WIH1);
  u16* wih2f = (u16*)(ws + WS_WIH2);
  u16* whh2f = (u16*)(ws + WS_WHH2);
  u16* wlinf = (u16*)(ws + WS_WLIN);
  float* b1  = (float*)(ws + WS_B1);
  float* b2  = (float*)(ws + WS_B2);
  u16* h1b   = (u16*)(ws + WS_H1);
  u16* h2b   = (u16*)(ws + WS_H2);

  __shared__ float plds[1024];    // 4 gates x 16x16 preacts

  const int tid = blockIdx.x * NTHR + threadIdx.x;

  // ---------------- phase 0: convert/pack (proven layout) ----------------
  for (int c = tid; c < T_ * B_ * I_ / 8; c += NBLK * NTHR)
    cvt8(xin + c * 8, xbf + c * 8);
  for (int c = tid; c < (1 << 17); c += NBLK * NTHR) {
    int lane = c & 63, kt = (c >> 6) & 15, g = (c >> 10) & 3, n = c >> 12;
    int row = g * 512 + n * 16 + (lane & 15);
    int k   = kt * 32 + (lane >> 4) * 8;
    cvt8(Whh1 + row * 512 + k, whh1f + c * 8);
  }
  for (int c = tid; c < (1 << 16); c += NBLK * NTHR) {
    int lane = c & 63, kt = (c >> 6) & 7, g = (c >> 9) & 3, n = c >> 11;
    int row = g * 512 + n * 16 + (lane & 15);
    int k   = kt * 32 + (lane >> 4) * 8;
    cvt8(Wih1 + row * 256 + k, wih1f + c * 8);
  }
  for (int c = tid; c < (1 << 17); c += NBLK * NTHR) {
    int lane = c & 63, kt = (c >> 6) & 15, g = (c >> 10) & 3, n = c >> 12;
    int row = g * 512 + n * 16 + (lane & 15);
    int k   = kt * 32 + (lane >> 4) * 8;
    cvt8(Wih2 + row * 512 + k, wih2f + c * 8);
    cvt8(Whh2 + row * 512 + k, whh2f + c * 8);
  }
  for (int c = tid; c < (1 << 14); c += NBLK * NTHR) {
    int lane = c & 63, kt = (c >> 6) & 15, nt = (c >> 10) & 1, l = c >> 11;
    int row = l * 32 + nt * 16 + (lane & 15);
    int k   = kt * 32 + (lane >> 4) * 8;
    cvt8(Wlin + row * 512 + k, wlinf + c * 8);
  }
  for (int c = tid; c < BH / 8; c += NBLK * NTHR) {
    cvt8(h10 + c * 8, h1b + c * 8);
    cvt8(h20 + c * 8, h2b + c * 8);
  }
  for (int i2 = tid; i2 < 2048; i2 += NBLK * NTHR) {
    b1[i2] = bih1[i2] + bhh1[i2];
    b2[i2] = bih2[i2] + bhh2[i2];
  }

  gbar0((u32*)(ctrl + CT_B0), NBLK);   // B0: packed data visible everywhere

  unsigned ep = 0;
  const int lane = threadIdx.x & 63;
  const int wv   = threadIdx.x >> 6;
  const int l15  = lane & 15;
  const int qd   = lane >> 4;

  if (blockIdx.x < NGB) {
    // ================= gate blocks: (nt, mt) tile, wave = gate =================
    const int nt = blockIdx.x >> 2;
    const int mt = blockIdx.x & 3;
    const int g  = wv;
    const int hcol   = nt * 16 + l15;
    const int ah_off = (mt * 16 + l15) * 512 + qd * 8;
    const int ax_off = (mt * 16 + l15) * 256 + qd * 8;
    const int row  = threadIdx.x >> 4;
    const int col  = threadIdx.x & 15;
    const int crow = mt * 16 + row;
    const int ccol = nt * 16 + col;

    bf16x8 Wr[16], Wx[8];
    #pragma unroll
    for (int kt = 0; kt < 16; kt++)
      Wr[kt] = ldg8(whh1f + ((nt * 4 + g) * 16 + kt) * 512 + lane * 8);
    #pragma unroll
    for (int kt = 0; kt < 8; kt++)
      Wx[kt] = ldg8(wih1f + ((nt * 4 + g) * 8 + kt) * 512 + lane * 8);

    const float bg = b1[g * 512 + hcol];
    float cS = c10[crow * 512 + ccol];

    f32x4 p = {bg, bg, bg, bg};
    #pragma unroll
    for (int kt = 0; kt < 8; kt++)
      p = MFMA16(ldg8(xbf + ax_off + kt * 32), Wx[kt], p);

    // -------- encoder --------
    for (int t = 0; t < T_; t++) {
      const u16* hr = h1b + (t & 1) * BH + ah_off;
      bf16x8 ah[16];
      #pragma unroll
      for (int kt = 0; kt < 16; kt++) ah[kt] = ald8(hr + kt * 32);
      const int t2 = (t + 1 < T_) ? t + 1 : 0;
      const u16* xr = xbf + t2 * (B_ * I_) + ax_off;
      bf16x8 ax[8];
      #pragma unroll
      for (int kt = 0; kt < 8; kt++) ax[kt] = ldg8(xr + kt * 32);

      f32x4 acc = p;
      #pragma unroll
      for (int kt = 0; kt < 16; kt++) acc = MFMA16(ah[kt], Wr[kt], acc);

      #pragma unroll
      for (int r = 0; r < 4; r++) plds[g * 256 + (qd * 4 + r) * 16 + l15] = acc[r];
      __syncthreads();
      {
        float gi = plds[threadIdx.x], gf = plds[256 + threadIdx.x];
        float gg = plds[512 + threadIdx.x], go = plds[768 + threadIdx.x];
        cS = sigm(gf) * cS + sigm(gi) * tanh_(gg);
        unsigned hv = f2bf(sigm(go) * tanh_(cS));
        unsigned ov = (unsigned)__shfl_xor((int)hv, 1);
        if (!(col & 1))
          __hip_atomic_store((u32*)(h1b + ((t + 1) & 1) * BH + crow * 512 + ccol),
                             hv | (ov << 16), __ATOMIC_RELAXED, __HIP_MEMORY_SCOPE_AGENT);
      }
      p = {bg, bg, bg, bg};
      #pragma unroll
      for (int kt = 0; kt < 8; kt++) p = MFMA16(ax[kt], Wx[kt], p);

      gbarF(cnt, (++ep) * NBLK);
    }

    // -------- phase 2: constant decoder input projection; reload W --------
    f32x4 q;
    {
      const float bg2 = b2[g * 512 + hcol];
      q = f32x4{bg2, bg2, bg2, bg2};
      const u16* hr = h1b + 0 + ah_off;   // h1T in buffer 0 (T even)
      #pragma unroll
      for (int kt = 0; kt < 16; kt++)
        q = MFMA16(ald8(hr + kt * 32),
                   ldg8(wih2f + ((nt * 4 + g) * 16 + kt) * 512 + lane * 8), q);
      #pragma unroll
      for (int kt = 0; kt < 16; kt++)
        Wr[kt] = ldg8(whh2f + ((nt * 4 + g) * 16 + kt) * 512 + lane * 8);
      cS = c20[crow * 512 + ccol];
    }
    gbarF(cnt, (++ep) * NBLK);   // B_mid

    // -------- decoder --------
    for (int t = 0; t < T_; t++) {
      const u16* hr = h2b + (t & 1) * BH + ah_off;
      bf16x8 ah[16];
      #pragma unroll
      for (int kt = 0; kt < 16; kt++) ah[kt] = ald8(hr + kt * 32);
      f32x4 acc = q;
      #pragma unroll
      for (int kt = 0; kt < 16; kt++) acc = MFMA16(ah[kt], Wr[kt], acc);
      #pragma unroll
      for (int r = 0; r < 4; r++) plds[g * 256 + (qd * 4 + r) * 16 + l15] = acc[r];
      __syncthreads();
      {
        float gi = plds[threadIdx.x], gf = plds[256 + threadIdx.x];
        float gg = plds[512 + threadIdx.x], go = plds[768 + threadIdx.x];
        cS = sigm(gf) * cS + sigm(gi) * tanh_(gg);
        unsigned hv = f2bf(sigm(go) * tanh_(cS));
        unsigned ov = (unsigned)__shfl_xor((int)hv, 1);
        if (!(col & 1))
          __hip_atomic_store((u32*)(h2b + ((t + 1) & 1) * BH + crow * 512 + ccol),
                             hv | (ov << 16), __ATOMIC_RELAXED, __HIP_MEMORY_SCOPE_AGENT);
      }
      gbarF(cnt, (++ep) * NBLK);
    }
  } else {
    // ================= linear blocks: wave = m-tile, block = n-tile ============
    const int j = blockIdx.x - NGB;
    const int ah_off = (wv * 16 + l15) * 512 + qd * 8;
    const int row0 = wv * 16 + qd * 4;

    bf16x8 Wl[16];
    #pragma unroll
    for (int kt = 0; kt < 16; kt++)
      Wl[kt] = ldg8(wlinf + (j * 16 + kt) * 512 + lane * 8);
    const float bl = blin[j * 16 + l15];

    for (int i3 = 0; i3 < T_ + 1; i3++) gbarF(cnt, (++ep) * NBLK);  // enc + mid

    // lag-1 pipeline: during decoder interval t compute out[t-1]
    for (int t = 0; t < T_; t++) {
      if (t >= 1) {
        const u16* hr = h2b + (t & 1) * BH + ah_off;
        f32x4 q0 = {bl, bl, bl, bl};
        #pragma unroll
        for (int kt = 0; kt < 16; kt++) q0 = MFMA16(ald8(hr + kt * 32), Wl[kt], q0);
        float* op = out + ((t - 1) * 64 + row0) * 256 + j * 16 + l15;
        #pragma unroll
        for (int r = 0; r < 4; r++) op[r * 256] = q0[r];
      }
      gbarF(cnt, (++ep) * NBLK);
    }
    {   // trailing: out[T-1] from final h2 (buffer 0)
      const u16* hr = h2b + 0 + ah_off;
      f32x4 q0 = {bl, bl, bl, bl};
      #pragma unroll
      for (int kt = 0; kt < 16; kt++) q0 = MFMA16(ald8(hr + kt * 32), Wl[kt], q0);
      float* op = out + ((T_ - 1) * 64 + row0) * 256 + j * 16 + l15;
      #pragma unroll
      for (int r = 0; r < 4; r++) op[r * 256] = q0[r];
    }
  }
}

extern "C" void kernel_launch(void* const* d_in, const int* in_sizes, int n_in,
                              void* d_out, int out_size, void* d_ws, size_t ws_size,
                              hipStream_t stream) {
  (void)in_sizes; (void)n_in; (void)out_size; (void)ws_size;
  const float* xin  = (const float*)d_in[0];
  const float* Wih1 = (const float*)d_in[1];
  const float* Whh1 = (const float*)d_in[2];
  const float* bih1 = (const float*)d_in[3];
  const float* bhh1 = (const float*)d_in[4];
  const float* Wih2 = (const float*)d_in[5];
  const float* Whh2 = (const float*)d_in[6];
  const float* bih2 = (const float*)d_in[7];
  const float* bhh2 = (const float*)d_in[8];
  const float* Wlin = (const float*)d_in[9];
  const float* blin = (const float*)d_in[10];
  const float* h10  = (const float*)d_in[11];
  const float* c10  = (const float*)d_in[12];
  const float* h20  = (const float*)d_in[13];
  const float* c20  = (const float*)d_in[14];
  float* out = (float*)d_out;
  char* ws   = (char*)d_ws;

  init_cnt<<<dim3(1), dim3(256), 0, stream>>>(ws);

  void* args[] = { (void*)&xin, (void*)&Wih1, (void*)&Whh1, (void*)&bih1, (void*)&bhh1,
                   (void*)&Wih2, (void*)&Whh2, (void*)&bih2, (void*)&bhh2,
                   (void*)&Wlin, (void*)&blin, (void*)&h10, (void*)&c10,
                   (void*)&h20, (void*)&c20, (void*)&out, (void*)&ws };
  hipLaunchCooperativeKernel((void*)lstm_ae_kernel, dim3(NBLK), dim3(NTHR),
                             args, 0, stream);
}

// Round 5
// 6162.855 us; speedup vs baseline: 1.9947x; 1.2472x over previous
//
#include <hip/hip_runtime.h>
#include <hip/hip_bf16.h>

// Problem constants
#define T_ 512
#define B_ 64
#define I_ 256
#define H_ 512
#define O_ 256
#define NGB 128             // gate blocks: 32 hcol-tiles x 4 m-tile domains; 4 waves = 4 gates
#define NLB 16              // linear blocks: 16 out n-tiles; 4 waves = 4 m-tiles
#define NBLK (NGB + NLB)
#define NTHR 256
#define BH (B_ * H_)

typedef unsigned short u16;
typedef unsigned int u32;
typedef unsigned long long u64;
typedef short bf16x8 __attribute__((ext_vector_type(8)));   // 16 B = 4 VGPRs
typedef float f32x4 __attribute__((ext_vector_type(4)));

// ---- control block (bytes 0..4095 of ws, zeroed by init_cnt) ----
#define CT_F1    0         // u32 f1[4][32]  : "h1{v} stored" flags per (mt,nt)
#define CT_F2    1024      // u32 f2[4][32]  : "h2{v} stored" flags per (mt,nt)
#define CT_LIN   2048      // u32 lin[16]    : linear block j finished reading h2{v-1}
#define CT_B0    2560      // one-time init barrier counter

// ---- workspace layout (bytes) ----
#define WS_XBF   4096
#define WS_WHH1  (WS_XBF   + 16777216)
#define WS_WIH1  (WS_WHH1  + 2097152)
#define WS_WIH2  (WS_WIH1  + 1048576)
#define WS_WHH2  (WS_WIH2  + 2097152)
#define WS_WLIN  (WS_WHH2  + 2097152)
#define WS_B1    (WS_WLIN  + 262144)
#define WS_B2    (WS_B1    + 8192)
#define WS_H1    (WS_B2    + 8192)      // h1 ring: 2 slots x BH bf16 = 131072
#define WS_H2    (WS_H1    + 131072)    // h2 ring: 4 slots x BH bf16 = 262144
#define WS_END   (WS_H2    + 262144)

__device__ __forceinline__ u16 f2bf(float f) {
  union { float f; unsigned u; } v; v.f = f;
  unsigned r = v.u + 0x7FFFu + ((v.u >> 16) & 1u);
  return (u16)(r >> 16);
}
__device__ __forceinline__ float sigm(float x)  { return 1.0f / (1.0f + __expf(-x)); }
__device__ __forceinline__ float tanh_(float x) { return 1.0f - 2.0f / (__expf(2.0f * x) + 1.0f); }
__device__ __forceinline__ bf16x8 ldg8(const u16* p) { return *(const bf16x8*)p; }
// agent-scope (LLC-coherent) 16B load: bypasses possibly-stale local L2
__device__ __forceinline__ bf16x8 ald8(const u16* p) {
  union { bf16x8 v; u64 q[2]; } u;
  u.q[0] = __hip_atomic_load((u64*)p,     __ATOMIC_RELAXED, __HIP_MEMORY_SCOPE_AGENT);
  u.q[1] = __hip_atomic_load((u64*)p + 1, __ATOMIC_RELAXED, __HIP_MEMORY_SCOPE_AGENT);
  return u.v;
}
#define MFMA16(a, b, c) __builtin_amdgcn_mfma_f32_16x16x32_bf16((a), (b), (c), 0, 0, 0)

__device__ __forceinline__ void cvt8(const float* s, u16* dst) {
  bf16x8 v;
  #pragma unroll
  for (int j = 0; j < 8; j++) v[j] = (short)f2bf(s[j]);
  *(bf16x8*)dst = v;
}

// Poll one flag word until >= tgt (values <= 514, int compare safe).
__device__ __forceinline__ void pollge(const u32* p, int tgt) {
  while ((int)__hip_atomic_load(p, __ATOMIC_RELAXED, __HIP_MEMORY_SCOPE_AGENT) < tgt)
    __builtin_amdgcn_s_sleep(1);
}

// One-time init barrier (heavy fences OK once: flushes packed weights/x to LLC).
__device__ __forceinline__ void gbar0(u32* cnt, unsigned target) {
  __syncthreads();
  if (threadIdx.x == 0) {
    __threadfence();
    __hip_atomic_fetch_add(cnt, 1u, __ATOMIC_RELAXED, __HIP_MEMORY_SCOPE_AGENT);
    while (__hip_atomic_load(cnt, __ATOMIC_RELAXED, __HIP_MEMORY_SCOPE_AGENT) < target)
      __builtin_amdgcn_s_sleep(2);
    __threadfence();
  }
  __syncthreads();
}

__global__ void init_cnt(char* ws) {
  for (int i = threadIdx.x; i < 1024; i += 256)
    __hip_atomic_store((u32*)ws + i, 0u, __ATOMIC_RELAXED, __HIP_MEMORY_SCOPE_AGENT);
}

__global__ void __launch_bounds__(NTHR, 1) lstm_ae_kernel(
    const float* __restrict__ xin,
    const float* __restrict__ Wih1, const float* __restrict__ Whh1,
    const float* __restrict__ bih1, const float* __restrict__ bhh1,
    const float* __restrict__ Wih2, const float* __restrict__ Whh2,
    const float* __restrict__ bih2, const float* __restrict__ bhh2,
    const float* __restrict__ Wlin, const float* __restrict__ blin,
    const float* __restrict__ h10, const float* __restrict__ c10,
    const float* __restrict__ h20, const float* __restrict__ c20,
    float* __restrict__ out, char* __restrict__ ws) {
  char* ctrl = ws;
  u32* f1    = (u32*)(ctrl + CT_F1);
  u32* f2    = (u32*)(ctrl + CT_F2);
  u32* linf  = (u32*)(ctrl + CT_LIN);
  u16* xbf   = (u16*)(ws + WS_XBF);
  u16* whh1f = (u16*)(ws + WS_WHH1);
  u16* wih1f = (u16*)(ws + WS_WIH1);
  u16* wih2f = (u16*)(ws + WS_WIH2);
  u16* whh2f = (u16*)(ws + WS_WHH2);
  u16* wlinf = (u16*)(ws + WS_WLIN);
  float* b1  = (float*)(ws + WS_B1);
  float* b2  = (float*)(ws + WS_B2);
  u16* h1r   = (u16*)(ws + WS_H1);    // 2-slot ring
  u16* h2r   = (u16*)(ws + WS_H2);    // 4-slot ring

  __shared__ float plds[1024];    // 4 gates x 16x16 preacts

  const int tid = blockIdx.x * NTHR + threadIdx.x;

  // ---------------- phase 0: convert/pack (proven layout) ----------------
  for (int c = tid; c < T_ * B_ * I_ / 8; c += NBLK * NTHR)
    cvt8(xin + c * 8, xbf + c * 8);
  for (int c = tid; c < (1 << 17); c += NBLK * NTHR) {
    int lane = c & 63, kt = (c >> 6) & 15, g = (c >> 10) & 3, n = c >> 12;
    int row = g * 512 + n * 16 + (lane & 15);
    int k   = kt * 32 + (lane >> 4) * 8;
    cvt8(Whh1 + row * 512 + k, whh1f + c * 8);
  }
  for (int c = tid; c < (1 << 16); c += NBLK * NTHR) {
    int lane = c & 63, kt = (c >> 6) & 7, g = (c >> 9) & 3, n = c >> 11;
    int row = g * 512 + n * 16 + (lane & 15);
    int k   = kt * 32 + (lane >> 4) * 8;
    cvt8(Wih1 + row * 256 + k, wih1f + c * 8);
  }
  for (int c = tid; c < (1 << 17); c += NBLK * NTHR) {
    int lane = c & 63, kt = (c >> 6) & 15, g = (c >> 10) & 3, n = c >> 12;
    int row = g * 512 + n * 16 + (lane & 15);
    int k   = kt * 32 + (lane >> 4) * 8;
    cvt8(Wih2 + row * 512 + k, wih2f + c * 8);
    cvt8(Whh2 + row * 512 + k, whh2f + c * 8);
  }
  for (int c = tid; c < (1 << 14); c += NBLK * NTHR) {
    int lane = c & 63, kt = (c >> 6) & 15, nt = (c >> 10) & 1, l = c >> 11;
    int row = l * 32 + nt * 16 + (lane & 15);
    int k   = kt * 32 + (lane >> 4) * 8;
    cvt8(Wlin + row * 512 + k, wlinf + c * 8);
  }
  for (int c = tid; c < BH / 8; c += NBLK * NTHR) {
    cvt8(h10 + c * 8, h1r + c * 8);     // h1{0} -> slot 0
    cvt8(h20 + c * 8, h2r + c * 8);     // h2{0} -> slot 0
  }
  for (int i2 = tid; i2 < 2048; i2 += NBLK * NTHR) {
    b1[i2] = bih1[i2] + bhh1[i2];
    b2[i2] = bih2[i2] + bhh2[i2];
  }

  gbar0((u32*)(ctrl + CT_B0), NBLK);   // B0: packed data visible everywhere

  const int lane = threadIdx.x & 63;
  const int wv   = threadIdx.x >> 6;
  const int l15  = lane & 15;
  const int qd   = lane >> 4;

  if (blockIdx.x < NGB) {
    // ================= gate blocks: (nt, mt) tile, wave = gate =================
    const int nt = blockIdx.x >> 2;
    const int mt = blockIdx.x & 3;
    const int g  = wv;
    const u32* f1d = f1 + mt * 32;     // my domain's h1 flags
    const u32* f2d = f2 + mt * 32;     // my domain's h2 flags
    const int hcol   = nt * 16 + l15;
    const int ah_off = (mt * 16 + l15) * 512 + qd * 8;
    const int ax_off = (mt * 16 + l15) * 256 + qd * 8;
    const int row  = threadIdx.x >> 4;
    const int col  = threadIdx.x & 15;
    const int crow = mt * 16 + row;
    const int ccol = nt * 16 + col;

    bf16x8 Wr[16], Wx[8];
    #pragma unroll
    for (int kt = 0; kt < 16; kt++)
      Wr[kt] = ldg8(whh1f + ((nt * 4 + g) * 16 + kt) * 512 + lane * 8);
    #pragma unroll
    for (int kt = 0; kt < 8; kt++)
      Wx[kt] = ldg8(wih1f + ((nt * 4 + g) * 8 + kt) * 512 + lane * 8);

    const float bg = b1[g * 512 + hcol];
    float cS = c10[crow * 512 + ccol];

    f32x4 p = {bg, bg, bg, bg};
    #pragma unroll
    for (int kt = 0; kt < 8; kt++)
      p = MFMA16(ldg8(xbf + ax_off + kt * 32), Wx[kt], p);

    // -------- encoder --------
    for (int t = 0; t < T_; t++) {
      if (lane < 32) pollge(f1d + lane, t);       // wait h1{t} from domain peers
      asm volatile("" ::: "memory");
      const u16* hr = h1r + (t & 1) * BH + ah_off;
      bf16x8 ah[16];
      #pragma unroll
      for (int kt = 0; kt < 16; kt++) ah[kt] = ald8(hr + kt * 32);
      const int t2 = (t + 1 < T_) ? t + 1 : 0;
      const u16* xr = xbf + t2 * (B_ * I_) + ax_off;
      bf16x8 ax[8];
      #pragma unroll
      for (int kt = 0; kt < 8; kt++) ax[kt] = ldg8(xr + kt * 32);

      f32x4 acc = p;
      #pragma unroll
      for (int kt = 0; kt < 16; kt++) acc = MFMA16(ah[kt], Wr[kt], acc);

      #pragma unroll
      for (int r = 0; r < 4; r++) plds[g * 256 + (qd * 4 + r) * 16 + l15] = acc[r];
      __syncthreads();
      {
        float gi = plds[threadIdx.x], gf = plds[256 + threadIdx.x];
        float gg = plds[512 + threadIdx.x], go = plds[768 + threadIdx.x];
        cS = sigm(gf) * cS + sigm(gi) * tanh_(gg);
        unsigned hv = f2bf(sigm(go) * tanh_(cS));
        unsigned ov = (unsigned)__shfl_xor((int)hv, 1);
        if (!(col & 1))
          __hip_atomic_store((u32*)(h1r + ((t + 1) & 1) * BH + crow * 512 + ccol),
                             hv | (ov << 16), __ATOMIC_RELAXED, __HIP_MEMORY_SCOPE_AGENT);
      }
      // x-projection for t+1 (overlaps store drain)
      p = {bg, bg, bg, bg};
      #pragma unroll
      for (int kt = 0; kt < 8; kt++) p = MFMA16(ax[kt], Wx[kt], p);

      asm volatile("s_waitcnt vmcnt(0)" ::: "memory");   // my h-stores at LLC
      __syncthreads();                                   // all waves drained
      if (threadIdx.x == 0)
        __hip_atomic_store((u32*)(f1d + nt), (u32)(t + 1),
                           __ATOMIC_RELAXED, __HIP_MEMORY_SCOPE_AGENT);
    }

    // -------- phase 2: decoder input projection (needs h1{T}) --------
    f32x4 q;
    {
      if (lane < 32) pollge(f1d + lane, T_);
      asm volatile("" ::: "memory");
      const float bg2 = b2[g * 512 + hcol];
      q = f32x4{bg2, bg2, bg2, bg2};
      const u16* hr = h1r + 0 + ah_off;   // h1{512} in slot 0 (T even)
      #pragma unroll
      for (int kt = 0; kt < 16; kt++)
        q = MFMA16(ald8(hr + kt * 32),
                   ldg8(wih2f + ((nt * 4 + g) * 16 + kt) * 512 + lane * 8), q);
      #pragma unroll
      for (int kt = 0; kt < 16; kt++)
        Wr[kt] = ldg8(whh2f + ((nt * 4 + g) * 16 + kt) * 512 + lane * 8);
      cS = c20[crow * 512 + ccol];
    }

    // -------- decoder --------
    for (int t = 0; t < T_; t++) {
      if (lane < 32) pollge(f2d + lane, t);               // wait h2{t}
      else if (lane < 48) pollge(linf + (lane - 32),      // ring back-pressure
                                 (t >= 4) ? t - 2 : 0);
      asm volatile("" ::: "memory");
      const u16* hr = h2r + (t & 3) * BH + ah_off;
      bf16x8 ah[16];
      #pragma unroll
      for (int kt = 0; kt < 16; kt++) ah[kt] = ald8(hr + kt * 32);
      f32x4 acc = q;
      #pragma unroll
      for (int kt = 0; kt < 16; kt++) acc = MFMA16(ah[kt], Wr[kt], acc);
      #pragma unroll
      for (int r = 0; r < 4; r++) plds[g * 256 + (qd * 4 + r) * 16 + l15] = acc[r];
      __syncthreads();
      {
        float gi = plds[threadIdx.x], gf = plds[256 + threadIdx.x];
        float gg = plds[512 + threadIdx.x], go = plds[768 + threadIdx.x];
        cS = sigm(gf) * cS + sigm(gi) * tanh_(gg);
        unsigned hv = f2bf(sigm(go) * tanh_(cS));
        unsigned ov = (unsigned)__shfl_xor((int)hv, 1);
        if (!(col & 1))
          __hip_atomic_store((u32*)(h2r + ((t + 1) & 3) * BH + crow * 512 + ccol),
                             hv | (ov << 16), __ATOMIC_RELAXED, __HIP_MEMORY_SCOPE_AGENT);
      }
      asm volatile("s_waitcnt vmcnt(0)" ::: "memory");
      __syncthreads();
      if (threadIdx.x == 0)
        __hip_atomic_store((u32*)(f2d + nt), (u32)(t + 1),
                           __ATOMIC_RELAXED, __HIP_MEMORY_SCOPE_AGENT);
    }
  } else {
    // ================= linear blocks: block = out n-tile, wave = m-tile ========
    const int j = blockIdx.x - NGB;
    const u32* f2w = f2 + wv * 32;      // wave wv consumes domain wv
    const int ah_off = (wv * 16 + l15) * 512 + qd * 8;
    const int row0 = wv * 16 + qd * 4;

    bf16x8 Wl[16];
    #pragma unroll
    for (int kt = 0; kt < 16; kt++)
      Wl[kt] = ldg8(wlinf + (j * 16 + kt) * 512 + lane * 8);
    const float bl = blin[j * 16 + l15];

    // out[s] = W_lin . h2{s+1}
    for (int s = 0; s < T_; s++) {
      if (lane < 32) pollge(f2w + lane, s + 1);
      asm volatile("" ::: "memory");
      const u16* hr = h2r + ((s + 1) & 3) * BH + ah_off;
      f32x4 q0 = {bl, bl, bl, bl};
      #pragma unroll
      for (int kt = 0; kt < 16; kt++) q0 = MFMA16(ald8(hr + kt * 32), Wl[kt], q0);
      float* op = out + (s * 64 + row0) * 256 + j * 16 + l15;
      #pragma unroll
      for (int r = 0; r < 4; r++) op[r * 256] = q0[r];
      __syncthreads();                  // all 4 waves consumed h2{s+1}
      if (threadIdx.x == 0)
        __hip_atomic_store((u32*)(linf + j), (u32)(s + 2),
                           __ATOMIC_RELAXED, __HIP_MEMORY_SCOPE_AGENT);
    }
  }
}

extern "C" void kernel_launch(void* const* d_in, const int* in_sizes, int n_in,
                              void* d_out, int out_size, void* d_ws, size_t ws_size,
                              hipStream_t stream) {
  (void)in_sizes; (void)n_in; (void)out_size; (void)ws_size;
  const float* xin  = (const float*)d_in[0];
  const float* Wih1 = (const float*)d_in[1];
  const float* Whh1 = (const float*)d_in[2];
  const float* bih1 = (const float*)d_in[3];
  const float* bhh1 = (const float*)d_in[4];
  const float* Wih2 = (const float*)d_in[5];
  const float* Whh2 = (const float*)d_in[6];
  const float* bih2 = (const float*)d_in[7];
  const float* bhh2 = (const float*)d_in[8];
  const float* Wlin = (const float*)d_in[9];
  const float* blin = (const float*)d_in[10];
  const float* h10  = (const float*)d_in[11];
  const float* c10  = (const float*)d_in[12];
  const float* h20  = (const float*)d_in[13];
  const float* c20  = (const float*)d_in[14];
  float* out = (float*)d_out;
  char* ws   = (char*)d_ws;

  init_cnt<<<dim3(1), dim3(256), 0, stream>>>(ws);

  void* args[] = { (void*)&xin, (void*)&Wih1, (void*)&Whh1, (void*)&bih1, (void*)&bhh1,
                   (void*)&Wih2, (void*)&Whh2, (void*)&bih2, (void*)&bhh2,
                   (void*)&Wlin, (void*)&blin, (void*)&h10, (void*)&c10,
                   (void*)&h20, (void*)&c20, (void*)&out, (void*)&ws };
  hipLaunchCooperativeKernel((void*)lstm_ae_kernel, dim3(NBLK), dim3(NTHR),
                             args, 0, stream);
}